// Round 2
// baseline (242.615 us; speedup 1.0000x reference)
//
#include <hip/hip_runtime.h>

#define NH 16
#define DH 64
#define SEQ 512
#define SIN 64
#define NBATCH 8

typedef short bf16x8 __attribute__((ext_vector_type(8)));
typedef float f32x4 __attribute__((ext_vector_type(4)));

__device__ __forceinline__ unsigned short f2bf(float f) {
  union { float f; unsigned u; } v; v.f = f;
  unsigned r = v.u + 0x7FFFu + ((v.u >> 16) & 1u);
  return (unsigned short)(r >> 16);
}
__device__ __forceinline__ float bf2f(unsigned short b) {
  union { unsigned u; float f; } v; v.u = ((unsigned)b) << 16;
  return v.f;
}
__device__ __forceinline__ f32x4 mfma16(bf16x8 a, bf16x8 b, f32x4 c) {
  return __builtin_amdgcn_mfma_f32_16x16x32_bf16(a, b, c, 0, 0, 0);
}
__device__ __forceinline__ void gload_lds16(const unsigned short* g, unsigned short* l) {
  __builtin_amdgcn_global_load_lds((const __attribute__((address_space(1))) void*)g,
                                   (__attribute__((address_space(3))) void*)l, 16, 0, 0);
}

// Stage a 64x64 bf16 tile (global row stride = gstride elems) into linear LDS
// [64][64] whose READS apply byte-swizzle  phys = colbyte ^ ((row&7)<<4).
// gload_lds writes linearly (base + lane*16B), so the swizzle is applied by
// permuting the per-lane GLOBAL source column (rule: linear dest + pre-swizzled
// source + swizzled read).
__device__ __forceinline__ void stage_tile_swz(const unsigned short* g, int gstride,
                                               unsigned short* lds, int w, int lane) {
  #pragma unroll
  for (int c = 0; c < 2; ++c) {
    const int row = w * 16 + c * 8 + (lane >> 3);
    const int cb = ((lane & 7) ^ (lane >> 3)) << 4;  // source byte-col
    gload_lds16(g + (size_t)row * gstride + (cb >> 1),
                lds + (w * 16 + c * 8) * 64);
  }
}
__device__ __forceinline__ bf16x8 read_swz(const unsigned short* lds, int row, int colbyte) {
  return *(const bf16x8*)((const char*)(lds + row * 64) + (colbyte ^ ((row & 7) << 4)));
}

// ---------------- convert kernels ----------------

__global__ __launch_bounds__(256) void k_convert_x(const float* __restrict__ hs,
                                                   const float* __restrict__ ihs,
                                                   unsigned short* __restrict__ X) {
  int idx = blockIdx.x * 256 + threadIdx.x;
  float4 v;
  if (idx < 1048576) v = ((const float4*)hs)[idx];
  else               v = ((const float4*)ihs)[idx - 1048576];
  ushort4 o; o.x = f2bf(v.x); o.y = f2bf(v.y); o.z = f2bf(v.z); o.w = f2bf(v.w);
  ((ushort4*)X)[idx] = o;
}

__global__ __launch_bounds__(256) void k_convert_e(const float* __restrict__ de,
                                                   unsigned short* __restrict__ E) {
  int idx = blockIdx.x * 256 + threadIdx.x;
  ushort4 o;
  if (idx < 16368) {
    float4 v = ((const float4*)de)[idx];
    o.x = f2bf(v.x); o.y = f2bf(v.y); o.z = f2bf(v.z); o.w = f2bf(v.w);
  } else { o.x = 0; o.y = 0; o.z = 0; o.w = 0; }
  ((ushort4*)E)[idx] = o;
}

__global__ __launch_bounds__(256) void k_convert_w(const float* __restrict__ Wq,
                                                   const float* __restrict__ Wk,
                                                   const float* __restrict__ Wv,
                                                   unsigned short* __restrict__ Wt) {
  __shared__ float t[64][65];
  const float* W = (blockIdx.z == 0) ? Wq : (blockIdx.z == 1) ? Wk : Wv;
  const int n0 = blockIdx.x * 64, k0 = blockIdx.y * 64;
  const int tid = threadIdx.x;
  #pragma unroll
  for (int q = 0; q < 4; ++q) {
    int s = q * 256 + tid;
    int r = s >> 4, c4 = s & 15;
    float4 v = *(const float4*)(W + (size_t)(k0 + r) * 1024 + n0 + c4 * 4);
    t[r][c4 * 4 + 0] = v.x; t[r][c4 * 4 + 1] = v.y;
    t[r][c4 * 4 + 2] = v.z; t[r][c4 * 4 + 3] = v.w;
  }
  __syncthreads();
  #pragma unroll
  for (int q = 0; q < 4; ++q) {
    int s = q * 256 + tid;
    int rn = s >> 4, c4 = s & 15;
    ushort4 o;
    o.x = f2bf(t[c4 * 4 + 0][rn]); o.y = f2bf(t[c4 * 4 + 1][rn]);
    o.z = f2bf(t[c4 * 4 + 2][rn]); o.w = f2bf(t[c4 * 4 + 3][rn]);
    *(ushort4*)(Wt + ((size_t)(blockIdx.z << 10) + n0 + rn) * 1024 + k0 + c4 * 4) = o;
  }
}

// ---------------- fused QKV GEMM (m97-style 128x128, BK=32) ----------------
__global__ __launch_bounds__(256) void k_gemm(const unsigned short* __restrict__ X,
                                              const unsigned short* __restrict__ Wt,
                                              const float* __restrict__ bq,
                                              const float* __restrict__ bk,
                                              const float* __restrict__ bv,
                                              unsigned short* __restrict__ Q,
                                              unsigned short* __restrict__ K,
                                              unsigned short* __restrict__ Vt,
                                              unsigned short* __restrict__ IK,
                                              unsigned short* __restrict__ IVt) {
  __shared__ unsigned short Asm[2][128 * 32];
  __shared__ unsigned short Bsm[2][128 * 32];
  const int tid = threadIdx.x, lane = tid & 63, w = tid >> 6;
  const int lg = lane >> 4, lc = lane & 15;
  const int m0 = blockIdx.y * 128, n0 = blockIdx.x * 128;
  const int wm = (w >> 1) * 64, wn = (w & 1) * 64;

  f32x4 acc[4][4];
  #pragma unroll
  for (int i = 0; i < 4; ++i)
    #pragma unroll
    for (int j = 0; j < 4; ++j) acc[i][j] = (f32x4){0.f, 0.f, 0.f, 0.f};

  #define STAGE(bi, kt)                                                          \
    {                                                                            \
      const int k0_ = (kt) * 32;                                                 \
      _Pragma("unroll")                                                          \
      for (int j_ = 0; j_ < 2; ++j_) {                                           \
        int c_ = w * 128 + j_ * 64 + lane;                                       \
        int r_ = c_ >> 2, cc_ = c_ & 3;                                          \
        gload_lds16(X + (size_t)(m0 + r_) * 1024 + k0_ + cc_ * 8,                \
                    &Asm[bi][(w * 128 + j_ * 64) * 8]);                          \
        gload_lds16(Wt + (size_t)(n0 + r_) * 1024 + k0_ + cc_ * 8,               \
                    &Bsm[bi][(w * 128 + j_ * 64) * 8]);                          \
      }                                                                          \
    }

  STAGE(0, 0);
  int cur = 0;
  for (int kt = 0; kt < 32; ++kt) {
    __syncthreads();
    if (kt + 1 < 32) STAGE(cur ^ 1, kt + 1);
    const unsigned short* A = Asm[cur];
    const unsigned short* B = Bsm[cur];
    bf16x8 af[4], bfr[4];
    #pragma unroll
    for (int i = 0; i < 4; ++i)
      af[i] = *(const bf16x8*)(A + (wm + i * 16 + lc) * 32 + lg * 8);
    #pragma unroll
    for (int j = 0; j < 4; ++j)
      bfr[j] = *(const bf16x8*)(B + (wn + j * 16 + lc) * 32 + lg * 8);
    #pragma unroll
    for (int i = 0; i < 4; ++i)
      #pragma unroll
      for (int j = 0; j < 4; ++j)
        acc[i][j] = mfma16(af[i], bfr[j], acc[i][j]);
    cur ^= 1;
  }
  #undef STAGE

  #pragma unroll
  for (int j = 0; j < 4; ++j) {
    const int gn = n0 + wn + j * 16 + lc;
    const int which = gn >> 10, nn = gn & 1023;
    const int hh = nn >> 6, dd = nn & 63;
    const float bias = (which == 0 ? bq : (which == 1 ? bk : bv))[nn];
    #pragma unroll
    for (int i = 0; i < 4; ++i) {
      #pragma unroll
      for (int ii = 0; ii < 4; ++ii) {
        const int gm = m0 + wm + i * 16 + lg * 4 + ii;
        const unsigned short o = f2bf(acc[i][j][ii] + bias);
        if (gm < 4096) {
          const int bb = gm >> 9, ss = gm & 511;
          if (which == 0)      Q[(((size_t)(bb * NH + hh) * 512 + ss) << 6) + dd] = o;
          else if (which == 1) K[(((size_t)(bb * NH + hh) * 512 + ss) << 6) + dd] = o;
          else                 Vt[((size_t)(bb * NH + hh) * 64 + dd) * 512 + ss] = o;
        } else {
          const int mi = gm - 4096, bb = mi >> 6, si = mi & 63;
          if (which == 1)      IK[((size_t)(bb * NH + hh) * 64 + si) * 64 + dd] = o;
          else if (which == 2) IVt[((size_t)(bb * NH + hh) * 64 + dd) * 64 + si] = o;
        }
      }
    }
  }
}

// ---------------- fused attention with relative-position bias ----------------
// Sheared bias tables: qds[l][ri] = q_l . E[l-ri+63+p0],  kds[r][li] = k_r . E[li-r+63+p0]
// LDS = 54,272 B  ->  3 blocks/CU (12 waves).
__global__ __launch_bounds__(256, 3) void k_attn(const unsigned short* __restrict__ Qg,
                                                 const unsigned short* __restrict__ Kg,
                                                 const unsigned short* __restrict__ Vtg,
                                                 const unsigned short* __restrict__ IKg,
                                                 const unsigned short* __restrict__ IVtg,
                                                 const unsigned short* __restrict__ Eg,
                                                 const float* __restrict__ mask,
                                                 const float* __restrict__ imask,
                                                 const float* __restrict__ gate,
                                                 float* __restrict__ out) {
  const int lt = blockIdx.x, h = blockIdx.y, b = blockIdx.z;
  const int l0 = lt * 64;
  const int tid = threadIdx.x;
  const int lane = tid & 63, w = tid >> 6;
  const int lg = lane >> 4, lc = lane & 15;
  const int bh = b * NH + h;

  __shared__ unsigned short Qs[64 * 72];   // padded linear
  __shared__ unsigned short Ks[64 * 64];   // swizzled (read_swz)
  __shared__ unsigned short Vts[64 * 64];  // swizzled
  __shared__ unsigned short qds[64 * 76];  // sheared bias, pitch 76
  __shared__ unsigned short kds[64 * 76];
  __shared__ unsigned short Ps[64 * 72];

  // stage Q tile
  {
    const unsigned short* g = Qg + ((size_t)(bh * 512 + l0)) * 64;
    #pragma unroll
    for (int q = 0; q < 2; ++q) {
      int ch = tid + q * 256, r = ch >> 3, c = ch & 7;
      *(uint4*)(&Qs[r * 72 + c * 8]) = *(const uint4*)(g + r * 64 + c * 8);
    }
  }

  f32x4 oacc[4];
  #pragma unroll
  for (int i = 0; i < 4; ++i) oacc[i] = (f32x4){0.f, 0.f, 0.f, 0.f};
  float mrun[4], lrun[4];
  #pragma unroll
  for (int i = 0; i < 4; ++i) { mrun[i] = -3.0e38f; lrun[i] = 0.f; }
  const float scale = 0.125f;
  const int ubase = 2 * w * 16;            // this wave's 32-wide u-slice base

  __syncthreads();

  for (int rt = 0; rt < 8; ++rt) {
    const int r0 = rt * 64;
    // ---- phase A: async K/V staging + qd MFMA + sheared qds write ----
    stage_tile_swz(Kg + ((size_t)(bh * 512 + r0)) * 64, 64, Ks, w, lane);
    stage_tile_swz(Vtg + (size_t)bh * 64 * 512 + r0, 512, Vts, w, lane);

    const int p0 = l0 - r0 + 448;
    bf16x8 eb[2][2];
    #pragma unroll
    for (int ns = 0; ns < 2; ++ns) {
      const int u = ubase + ns * 16 + lc;
      const unsigned short* ep = Eg + (size_t)(p0 + u) * 64 + lg * 8;
      eb[ns][0] = *(const bf16x8*)(ep);
      eb[ns][1] = *(const bf16x8*)(ep + 32);
    }
    {
      f32x4 da[4][2];
      #pragma unroll
      for (int ms = 0; ms < 4; ++ms) { da[ms][0] = (f32x4){0,0,0,0}; da[ms][1] = (f32x4){0,0,0,0}; }
      #pragma unroll
      for (int kc = 0; kc < 2; ++kc)
        #pragma unroll
        for (int ms = 0; ms < 4; ++ms) {
          bf16x8 a = *(const bf16x8*)(&Qs[(ms * 16 + lc) * 72 + kc * 32 + lg * 8]);
          da[ms][0] = mfma16(a, eb[0][kc], da[ms][0]);
          da[ms][1] = mfma16(a, eb[1][kc], da[ms][1]);
        }
      #pragma unroll
      for (int ms = 0; ms < 4; ++ms)
        #pragma unroll
        for (int ns = 0; ns < 2; ++ns) {
          const int u = ubase + ns * 16 + lc;
          #pragma unroll
          for (int i = 0; i < 4; ++i) {
            const int l = ms * 16 + lg * 4 + i;
            const int ri = l - u + 63;
            if ((unsigned)ri < 64u) qds[l * 76 + ri] = f2bf(da[ms][ns][i]);
          }
        }
    }
    __syncthreads();   // K/V staged (vmcnt drained), qds visible

    // ---- phase B: kd MFMA + sheared kds write, QK^T ----
    {
      f32x4 da[4][2];
      #pragma unroll
      for (int ms = 0; ms < 4; ++ms) { da[ms][0] = (f32x4){0,0,0,0}; da[ms][1] = (f32x4){0,0,0,0}; }
      #pragma unroll
      for (int kc = 0; kc < 2; ++kc)
        #pragma unroll
        for (int ms = 0; ms < 4; ++ms) {
          bf16x8 a = read_swz(Ks, ms * 16 + lc, kc * 64 + lg * 16);
          da[ms][0] = mfma16(a, eb[0][kc], da[ms][0]);
          da[ms][1] = mfma16(a, eb[1][kc], da[ms][1]);
        }
      #pragma unroll
      for (int ms = 0; ms < 4; ++ms)
        #pragma unroll
        for (int ns = 0; ns < 2; ++ns) {
          const int u = ubase + ns * 16 + lc;
          #pragma unroll
          for (int i = 0; i < 4; ++i) {
            const int r = ms * 16 + lg * 4 + i;
            const int li = r + u - 63;
            if ((unsigned)li < 64u) kds[r * 76 + li] = f2bf(da[ms][ns][i]);
          }
        }
    }
    f32x4 sacc[4];
    #pragma unroll
    for (int ns = 0; ns < 4; ++ns) sacc[ns] = (f32x4){0.f, 0.f, 0.f, 0.f};
    #pragma unroll
    for (int kc = 0; kc < 2; ++kc) {
      bf16x8 qa = *(const bf16x8*)(&Qs[(w * 16 + lc) * 72 + kc * 32 + lg * 8]);
      #pragma unroll
      for (int ns = 0; ns < 4; ++ns) {
        bf16x8 kb = read_swz(Ks, ns * 16 + lc, kc * 64 + lg * 16);
        sacc[ns] = mfma16(qa, kb, sacc[ns]);
      }
    }
    __syncthreads();   // kds visible

    // ---- phase C: bias add + online softmax + PV ----
    float sv[4][4];
    #pragma unroll
    for (int ns = 0; ns < 4; ++ns) {
      const float mk = mask[b * SEQ + r0 + ns * 16 + lc];
      const int ri = ns * 16 + lc;
      #pragma unroll
      for (int i = 0; i < 4; ++i) {
        const int li = w * 16 + lg * 4 + i;
        float x = sacc[ns][i] + bf2f(qds[li * 76 + ri]) + bf2f(kds[ri * 76 + li]);
        sv[ns][i] = x * scale + mk;
      }
    }
    #pragma unroll
    for (int i = 0; i < 4; ++i) {
      float mt = fmaxf(fmaxf(sv[0][i], sv[1][i]), fmaxf(sv[2][i], sv[3][i]));
      #pragma unroll
      for (int m = 1; m <= 8; m <<= 1) mt = fmaxf(mt, __shfl_xor(mt, m));
      const float mnew = fmaxf(mrun[i], mt);
      const float fr = __expf(mrun[i] - mnew);
      mrun[i] = mnew;
      float ps = 0.f;
      #pragma unroll
      for (int ns = 0; ns < 4; ++ns) { float p = __expf(sv[ns][i] - mnew); sv[ns][i] = p; ps += p; }
      #pragma unroll
      for (int m = 1; m <= 8; m <<= 1) ps += __shfl_xor(ps, m);
      lrun[i] = lrun[i] * fr + ps;
      #pragma unroll
      for (int ds = 0; ds < 4; ++ds) oacc[ds][i] *= fr;
    }
    #pragma unroll
    for (int ns = 0; ns < 4; ++ns)
      #pragma unroll
      for (int i = 0; i < 4; ++i)
        Ps[(w * 16 + lg * 4 + i) * 72 + ns * 16 + lc] = f2bf(sv[ns][i]);
    #pragma unroll
    for (int kc = 0; kc < 2; ++kc) {
      bf16x8 pa = *(const bf16x8*)(&Ps[(w * 16 + lc) * 72 + kc * 32 + lg * 8]);
      #pragma unroll
      for (int ds = 0; ds < 4; ++ds) {
        bf16x8 vb = read_swz(Vts, ds * 16 + lc, kc * 64 + lg * 16);
        oacc[ds] = mfma16(pa, vb, oacc[ds]);
      }
    }
    __syncthreads();   // free Ks/Vts/qds/kds for next iteration
  }

  // ---- instruct branch ----
  {
    stage_tile_swz(IKg + (size_t)bh * 4096, 64, Ks, w, lane);
    stage_tile_swz(IVtg + (size_t)bh * 4096, 64, Vts, w, lane);
    __syncthreads();
    f32x4 sacc[4];
    #pragma unroll
    for (int ns = 0; ns < 4; ++ns) sacc[ns] = (f32x4){0.f, 0.f, 0.f, 0.f};
    #pragma unroll
    for (int kc = 0; kc < 2; ++kc) {
      bf16x8 qa = *(const bf16x8*)(&Qs[(w * 16 + lc) * 72 + kc * 32 + lg * 8]);
      #pragma unroll
      for (int ns = 0; ns < 4; ++ns) {
        bf16x8 kb = read_swz(Ks, ns * 16 + lc, kc * 64 + lg * 16);
        sacc[ns] = mfma16(qa, kb, sacc[ns]);
      }
    }
    float sv[4][4], isum[4];
    #pragma unroll
    for (int ns = 0; ns < 4; ++ns) {
      const float mk = imask[b * SIN + ns * 16 + lc];
      #pragma unroll
      for (int i = 0; i < 4; ++i) sv[ns][i] = sacc[ns][i] * scale + mk;
    }
    #pragma unroll
    for (int i = 0; i < 4; ++i) {
      float mt = fmaxf(fmaxf(sv[0][i], sv[1][i]), fmaxf(sv[2][i], sv[3][i]));
      #pragma unroll
      for (int m = 1; m <= 8; m <<= 1) mt = fmaxf(mt, __shfl_xor(mt, m));
      float ps = 0.f;
      #pragma unroll
      for (int ns = 0; ns < 4; ++ns) { float p = __expf(sv[ns][i] - mt); sv[ns][i] = p; ps += p; }
      #pragma unroll
      for (int m = 1; m <= 8; m <<= 1) ps += __shfl_xor(ps, m);
      isum[i] = ps;
    }
    #pragma unroll
    for (int ns = 0; ns < 4; ++ns)
      #pragma unroll
      for (int i = 0; i < 4; ++i)
        Ps[(w * 16 + lg * 4 + i) * 72 + ns * 16 + lc] = f2bf(sv[ns][i]);
    f32x4 iacc[4];
    #pragma unroll
    for (int ds = 0; ds < 4; ++ds) iacc[ds] = (f32x4){0.f, 0.f, 0.f, 0.f};
    #pragma unroll
    for (int kc = 0; kc < 2; ++kc) {
      bf16x8 pa = *(const bf16x8*)(&Ps[(w * 16 + lc) * 72 + kc * 32 + lg * 8]);
      #pragma unroll
      for (int ds = 0; ds < 4; ++ds) {
        bf16x8 vb = read_swz(Vts, ds * 16 + lc, kc * 64 + lg * 16);
        iacc[ds] = mfma16(pa, vb, iacc[ds]);
      }
    }
    const float tg = tanhf(gate[h]);
    #pragma unroll
    for (int ds = 0; ds < 4; ++ds)
      #pragma unroll
      for (int i = 0; i < 4; ++i) {
        const int li = w * 16 + lg * 4 + i;
        const float val = oacc[ds][i] / lrun[i] + tg * (iacc[ds][i] / isum[i]);
        out[(size_t)(b * SEQ + l0 + li) * 1024 + h * 64 + ds * 16 + lc] = val;
      }
  }
}

// ---------------- launch ----------------

extern "C" void kernel_launch(void* const* d_in, const int* in_sizes, int n_in,
                              void* d_out, int out_size, void* d_ws, size_t ws_size,
                              hipStream_t stream) {
  (void)in_sizes; (void)n_in; (void)out_size; (void)ws_size;
  const float* hs    = (const float*)d_in[0];
  const float* ihs   = (const float*)d_in[1];
  const float* mask  = (const float*)d_in[2];
  const float* imask = (const float*)d_in[3];
  const float* Wq    = (const float*)d_in[4];
  const float* bq    = (const float*)d_in[5];
  const float* Wk    = (const float*)d_in[6];
  const float* bk    = (const float*)d_in[7];
  const float* Wv    = (const float*)d_in[8];
  const float* bv    = (const float*)d_in[9];
  const float* de    = (const float*)d_in[10];
  const float* gate  = (const float*)d_in[11];
  float* out = (float*)d_out;

  char* ws = (char*)d_ws;
  size_t off = 0;
  auto alloc = [&](size_t bytes) -> void* {
    void* p = ws + off;
    off += (bytes + 255) & ~(size_t)255;
    return p;
  };
  unsigned short* X    = (unsigned short*)alloc((size_t)4608 * 1024 * 2);
  unsigned short* Wt   = (unsigned short*)alloc((size_t)3072 * 1024 * 2);
  unsigned short* E    = (unsigned short*)alloc((size_t)1024 * 64 * 2);
  unsigned short* Qb   = (unsigned short*)alloc((size_t)8 * 16 * 512 * 64 * 2);
  unsigned short* Kb   = (unsigned short*)alloc((size_t)8 * 16 * 512 * 64 * 2);
  unsigned short* Vtb  = (unsigned short*)alloc((size_t)8 * 16 * 64 * 512 * 2);
  unsigned short* IKb  = (unsigned short*)alloc((size_t)8 * 16 * 64 * 64 * 2);
  unsigned short* IVtb = (unsigned short*)alloc((size_t)8 * 16 * 64 * 64 * 2);

  k_convert_x<<<4608, 256, 0, stream>>>(hs, ihs, X);
  k_convert_w<<<dim3(16, 16, 3), 256, 0, stream>>>(Wq, Wk, Wv, Wt);
  k_convert_e<<<64, 256, 0, stream>>>(de, E);
  k_gemm<<<dim3(24, 36), 256, 0, stream>>>(X, Wt, bq, bk, bv, Qb, Kb, Vtb, IKb, IVtb);
  k_attn<<<dim3(8, 16, 8), 256, 0, stream>>>(Qb, Kb, Vtb, IKb, IVtb, E, mask, imask, gate, out);
}

// Round 3
// 186.756 us; speedup vs baseline: 1.2991x; 1.2991x over previous
//
#include <hip/hip_runtime.h>

#define NH 16
#define DH 64
#define SEQ 512
#define SIN 64
#define NBATCH 8

typedef short bf16x8 __attribute__((ext_vector_type(8)));
typedef float f32x4 __attribute__((ext_vector_type(4)));

__device__ __forceinline__ unsigned short f2bf(float f) {
  union { float f; unsigned u; } v; v.f = f;
  unsigned r = v.u + 0x7FFFu + ((v.u >> 16) & 1u);
  return (unsigned short)(r >> 16);
}
__device__ __forceinline__ float bf2f(unsigned short b) {
  union { unsigned u; float f; } v; v.u = ((unsigned)b) << 16;
  return v.f;
}
__device__ __forceinline__ f32x4 mfma16(bf16x8 a, bf16x8 b, f32x4 c) {
  return __builtin_amdgcn_mfma_f32_16x16x32_bf16(a, b, c, 0, 0, 0);
}
__device__ __forceinline__ void gload_lds16(const unsigned short* g, unsigned short* l) {
  __builtin_amdgcn_global_load_lds((const __attribute__((address_space(1))) void*)g,
                                   (__attribute__((address_space(3))) void*)l, 16, 0, 0);
}

// 64x64 bf16 tile in LDS, logical row-major [64][64], physical byte swizzle
// phys_byte = row*128 + (colbyte ^ ((row&7)<<4)).  Conflict-free for b128 reads
// of 16-lane column slices (verified R2 on HW).
__device__ __forceinline__ void stage_tile_swz(const unsigned short* g, int gstride,
                                               unsigned short* lds, int w, int lane) {
  #pragma unroll
  for (int c = 0; c < 2; ++c) {
    const int row = w * 16 + c * 8 + (lane >> 3);
    const int cb = ((lane & 7) ^ (lane >> 3)) << 4;  // pre-swizzled source byte-col
    gload_lds16(g + (size_t)row * gstride + (cb >> 1),
                lds + (w * 16 + c * 8) * 64);
  }
}
__device__ __forceinline__ bf16x8 read_swz(const unsigned short* lds, int row, int colbyte) {
  return *(const bf16x8*)((const char*)(lds + row * 64) + (colbyte ^ ((row & 7) << 4)));
}

// ---------------- convert kernels ----------------

__global__ __launch_bounds__(256) void k_convert_x(const float* __restrict__ hs,
                                                   const float* __restrict__ ihs,
                                                   unsigned short* __restrict__ X) {
  int idx = blockIdx.x * 256 + threadIdx.x;
  float4 v;
  if (idx < 1048576) v = ((const float4*)hs)[idx];
  else               v = ((const float4*)ihs)[idx - 1048576];
  ushort4 o; o.x = f2bf(v.x); o.y = f2bf(v.y); o.z = f2bf(v.z); o.w = f2bf(v.w);
  ((ushort4*)X)[idx] = o;
}

__global__ __launch_bounds__(256) void k_convert_e(const float* __restrict__ de,
                                                   unsigned short* __restrict__ E) {
  int idx = blockIdx.x * 256 + threadIdx.x;
  ushort4 o;
  if (idx < 16368) {
    float4 v = ((const float4*)de)[idx];
    o.x = f2bf(v.x); o.y = f2bf(v.y); o.z = f2bf(v.z); o.w = f2bf(v.w);
  } else { o.x = 0; o.y = 0; o.z = 0; o.w = 0; }
  ((ushort4*)E)[idx] = o;
}

__global__ __launch_bounds__(256) void k_convert_w(const float* __restrict__ Wq,
                                                   const float* __restrict__ Wk,
                                                   const float* __restrict__ Wv,
                                                   unsigned short* __restrict__ Wt) {
  __shared__ float t[64][65];
  const float* W = (blockIdx.z == 0) ? Wq : (blockIdx.z == 1) ? Wk : Wv;
  const int n0 = blockIdx.x * 64, k0 = blockIdx.y * 64;
  const int tid = threadIdx.x;
  #pragma unroll
  for (int q = 0; q < 4; ++q) {
    int s = q * 256 + tid;
    int r = s >> 4, c4 = s & 15;
    float4 v = *(const float4*)(W + (size_t)(k0 + r) * 1024 + n0 + c4 * 4);
    t[r][c4 * 4 + 0] = v.x; t[r][c4 * 4 + 1] = v.y;
    t[r][c4 * 4 + 2] = v.z; t[r][c4 * 4 + 3] = v.w;
  }
  __syncthreads();
  #pragma unroll
  for (int q = 0; q < 4; ++q) {
    int s = q * 256 + tid;
    int rn = s >> 4, c4 = s & 15;
    ushort4 o;
    o.x = f2bf(t[c4 * 4 + 0][rn]); o.y = f2bf(t[c4 * 4 + 1][rn]);
    o.z = f2bf(t[c4 * 4 + 2][rn]); o.w = f2bf(t[c4 * 4 + 3][rn]);
    *(ushort4*)(Wt + ((size_t)(blockIdx.z << 10) + n0 + rn) * 1024 + k0 + c4 * 4) = o;
  }
}

// ---------------- fused QKV GEMM (m97-style 128x128, BK=32) ----------------
__global__ __launch_bounds__(256) void k_gemm(const unsigned short* __restrict__ X,
                                              const unsigned short* __restrict__ Wt,
                                              const float* __restrict__ bq,
                                              const float* __restrict__ bk,
                                              const float* __restrict__ bv,
                                              unsigned short* __restrict__ Q,
                                              unsigned short* __restrict__ K,
                                              unsigned short* __restrict__ Vt,
                                              unsigned short* __restrict__ IK,
                                              unsigned short* __restrict__ IVt) {
  __shared__ unsigned short Asm[2][128 * 32];
  __shared__ unsigned short Bsm[2][128 * 32];
  const int tid = threadIdx.x, lane = tid & 63, w = tid >> 6;
  const int lg = lane >> 4, lc = lane & 15;
  const int m0 = blockIdx.y * 128, n0 = blockIdx.x * 128;
  const int wm = (w >> 1) * 64, wn = (w & 1) * 64;

  f32x4 acc[4][4];
  #pragma unroll
  for (int i = 0; i < 4; ++i)
    #pragma unroll
    for (int j = 0; j < 4; ++j) acc[i][j] = (f32x4){0.f, 0.f, 0.f, 0.f};

  #define STAGE(bi, kt)                                                          \
    {                                                                            \
      const int k0_ = (kt) * 32;                                                 \
      _Pragma("unroll")                                                          \
      for (int j_ = 0; j_ < 2; ++j_) {                                           \
        int c_ = w * 128 + j_ * 64 + lane;                                       \
        int r_ = c_ >> 2, cc_ = c_ & 3;                                          \
        gload_lds16(X + (size_t)(m0 + r_) * 1024 + k0_ + cc_ * 8,                \
                    &Asm[bi][(w * 128 + j_ * 64) * 8]);                          \
        gload_lds16(Wt + (size_t)(n0 + r_) * 1024 + k0_ + cc_ * 8,               \
                    &Bsm[bi][(w * 128 + j_ * 64) * 8]);                          \
      }                                                                          \
    }

  STAGE(0, 0);
  int cur = 0;
  for (int kt = 0; kt < 32; ++kt) {
    __syncthreads();
    if (kt + 1 < 32) STAGE(cur ^ 1, kt + 1);
    const unsigned short* A = Asm[cur];
    const unsigned short* B = Bsm[cur];
    bf16x8 af[4], bfr[4];
    #pragma unroll
    for (int i = 0; i < 4; ++i)
      af[i] = *(const bf16x8*)(A + (wm + i * 16 + lc) * 32 + lg * 8);
    #pragma unroll
    for (int j = 0; j < 4; ++j)
      bfr[j] = *(const bf16x8*)(B + (wn + j * 16 + lc) * 32 + lg * 8);
    #pragma unroll
    for (int i = 0; i < 4; ++i)
      #pragma unroll
      for (int j = 0; j < 4; ++j)
        acc[i][j] = mfma16(af[i], bfr[j], acc[i][j]);
    cur ^= 1;
  }
  #undef STAGE

  #pragma unroll
  for (int j = 0; j < 4; ++j) {
    const int gn = n0 + wn + j * 16 + lc;
    const int which = gn >> 10, nn = gn & 1023;
    const int hh = nn >> 6, dd = nn & 63;
    const float bias = (which == 0 ? bq : (which == 1 ? bk : bv))[nn];
    #pragma unroll
    for (int i = 0; i < 4; ++i) {
      #pragma unroll
      for (int ii = 0; ii < 4; ++ii) {
        const int gm = m0 + wm + i * 16 + lg * 4 + ii;
        const unsigned short o = f2bf(acc[i][j][ii] + bias);
        if (gm < 4096) {
          const int bb = gm >> 9, ss = gm & 511;
          if (which == 0)      Q[(((size_t)(bb * NH + hh) * 512 + ss) << 6) + dd] = o;
          else if (which == 1) K[(((size_t)(bb * NH + hh) * 512 + ss) << 6) + dd] = o;
          else                 Vt[((size_t)(bb * NH + hh) * 64 + dd) * 512 + ss] = o;
        } else {
          const int mi = gm - 4096, bb = mi >> 6, si = mi & 63;
          if (which == 1)      IK[((size_t)(bb * NH + hh) * 64 + si) * 64 + dd] = o;
          else if (which == 2) IVt[((size_t)(bb * NH + hh) * 64 + dd) * 64 + si] = o;
        }
      }
    }
  }
}

// ---------------- fused attention with relative-position bias ----------------
// 2 barriers per K-tile.  Phase A: stage K/V (async) + qd/kd bias MFMAs
// (kd A-fragments read from GLOBAL K so phase A doesn't depend on staging).
// Phase B: QK^T + sheared-gather bias + online softmax + PV.
// LDS = 52,224 B -> 3 blocks/CU; no launch-bounds reg clamp (R2 spill lesson).
__global__ __launch_bounds__(256) void k_attn(const unsigned short* __restrict__ Qg,
                                              const unsigned short* __restrict__ Kg,
                                              const unsigned short* __restrict__ Vtg,
                                              const unsigned short* __restrict__ IKg,
                                              const unsigned short* __restrict__ IVtg,
                                              const unsigned short* __restrict__ Eg,
                                              const float* __restrict__ mask,
                                              const float* __restrict__ imask,
                                              const float* __restrict__ gate,
                                              float* __restrict__ out) {
  const int lt = blockIdx.x, h = blockIdx.y, b = blockIdx.z;
  const int l0 = lt * 64;
  const int tid = threadIdx.x;
  const int lane = tid & 63, w = tid >> 6;
  const int lg = lane >> 4, lc = lane & 15;
  const int bh = b * NH + h;

  __shared__ unsigned short Qs[64 * 64];   // swizzled
  __shared__ unsigned short Ks[64 * 64];   // swizzled
  __shared__ unsigned short Vts[64 * 64];  // swizzled
  __shared__ unsigned short Ps[64 * 64];   // swizzled
  __shared__ unsigned short qds[64 * 76];  // sheared bias, pitch 76 (scalar access)
  __shared__ unsigned short kds[64 * 76];

  // stage Q tile (swizzled write: chunk c -> c ^ (r&7))
  {
    const unsigned short* g = Qg + ((size_t)(bh * 512 + l0)) * 64;
    #pragma unroll
    for (int q = 0; q < 2; ++q) {
      int ch = tid + q * 256, r = ch >> 3, c = ch & 7;
      *(uint4*)(&Qs[r * 64 + ((c ^ (r & 7)) << 3)]) = *(const uint4*)(g + r * 64 + c * 8);
    }
  }

  f32x4 oacc[4];
  #pragma unroll
  for (int i = 0; i < 4; ++i) oacc[i] = (f32x4){0.f, 0.f, 0.f, 0.f};
  float mrun[4], lrun[4];
  #pragma unroll
  for (int i = 0; i < 4; ++i) { mrun[i] = -3.0e38f; lrun[i] = 0.f; }
  const float scale = 0.125f;
  const int ubase = w * 32;                 // this wave's 32-wide u-slice

  __syncthreads();

  for (int rt = 0; rt < 8; ++rt) {
    const int r0 = rt * 64;
    const unsigned short* kg = Kg + ((size_t)(bh * 512 + r0)) * 64;

    // ---- phase A: async K/V staging + qd/kd bias MFMAs (no Ks dependence) ----
    stage_tile_swz(kg, 64, Ks, w, lane);
    stage_tile_swz(Vtg + (size_t)bh * 64 * 512 + r0, 512, Vts, w, lane);

    const int p0 = l0 - r0 + 448;
    bf16x8 eb[2][2];
    #pragma unroll
    for (int ns = 0; ns < 2; ++ns) {
      const int u = ubase + ns * 16 + lc;
      const unsigned short* ep = Eg + (size_t)(p0 + u) * 64 + lg * 8;
      eb[ns][0] = *(const bf16x8*)(ep);
      eb[ns][1] = *(const bf16x8*)(ep + 32);
    }
    {
      f32x4 da[4][2];   // qd: A = Q rows (LDS, swizzled)
      #pragma unroll
      for (int ms = 0; ms < 4; ++ms) { da[ms][0] = (f32x4){0,0,0,0}; da[ms][1] = (f32x4){0,0,0,0}; }
      #pragma unroll
      for (int kc = 0; kc < 2; ++kc)
        #pragma unroll
        for (int ms = 0; ms < 4; ++ms) {
          bf16x8 a = read_swz(Qs, ms * 16 + lc, kc * 64 + lg * 16);
          da[ms][0] = mfma16(a, eb[0][kc], da[ms][0]);
          da[ms][1] = mfma16(a, eb[1][kc], da[ms][1]);
        }
      #pragma unroll
      for (int ms = 0; ms < 4; ++ms)
        #pragma unroll
        for (int ns = 0; ns < 2; ++ns) {
          const int u = ubase + ns * 16 + lc;
          #pragma unroll
          for (int i = 0; i < 4; ++i) {
            const int l = ms * 16 + lg * 4 + i;
            const int ri = l - u + 63;
            if ((unsigned)ri < 64u) qds[l * 76 + ri] = f2bf(da[ms][ns][i]);
          }
        }
      // kd: A = K rows straight from GLOBAL (L2-hot, row = one 128B line)
      #pragma unroll
      for (int ms = 0; ms < 4; ++ms) { da[ms][0] = (f32x4){0,0,0,0}; da[ms][1] = (f32x4){0,0,0,0}; }
      #pragma unroll
      for (int kc = 0; kc < 2; ++kc)
        #pragma unroll
        for (int ms = 0; ms < 4; ++ms) {
          bf16x8 a = *(const bf16x8*)(kg + (size_t)(ms * 16 + lc) * 64 + kc * 32 + lg * 8);
          da[ms][0] = mfma16(a, eb[0][kc], da[ms][0]);
          da[ms][1] = mfma16(a, eb[1][kc], da[ms][1]);
        }
      #pragma unroll
      for (int ms = 0; ms < 4; ++ms)
        #pragma unroll
        for (int ns = 0; ns < 2; ++ns) {
          const int u = ubase + ns * 16 + lc;
          #pragma unroll
          for (int i = 0; i < 4; ++i) {
            const int r = ms * 16 + lg * 4 + i;
            const int li = r + u - 63;
            if ((unsigned)li < 64u) kds[r * 76 + li] = f2bf(da[ms][ns][i]);
          }
        }
    }
    __syncthreads();   // staging drained; qds/kds visible

    // ---- phase B: QK^T + bias gather + online softmax + PV ----
    f32x4 sacc[4];
    #pragma unroll
    for (int ns = 0; ns < 4; ++ns) sacc[ns] = (f32x4){0.f, 0.f, 0.f, 0.f};
    #pragma unroll
    for (int kc = 0; kc < 2; ++kc) {
      bf16x8 qa = read_swz(Qs, w * 16 + lc, kc * 64 + lg * 16);
      #pragma unroll
      for (int ns = 0; ns < 4; ++ns) {
        bf16x8 kb = read_swz(Ks, ns * 16 + lc, kc * 64 + lg * 16);
        sacc[ns] = mfma16(qa, kb, sacc[ns]);
      }
    }
    float sv[4][4];
    #pragma unroll
    for (int ns = 0; ns < 4; ++ns) {
      const float mk = mask[b * SEQ + r0 + ns * 16 + lc];
      const int ri = ns * 16 + lc;
      #pragma unroll
      for (int i = 0; i < 4; ++i) {
        const int li = w * 16 + lg * 4 + i;
        float x = sacc[ns][i] + bf2f(qds[li * 76 + ri]) + bf2f(kds[ri * 76 + li]);
        sv[ns][i] = x * scale + mk;
      }
    }
    #pragma unroll
    for (int i = 0; i < 4; ++i) {
      float mt = fmaxf(fmaxf(sv[0][i], sv[1][i]), fmaxf(sv[2][i], sv[3][i]));
      #pragma unroll
      for (int m = 1; m <= 8; m <<= 1) mt = fmaxf(mt, __shfl_xor(mt, m));
      const float mnew = fmaxf(mrun[i], mt);
      const float fr = __expf(mrun[i] - mnew);
      mrun[i] = mnew;
      float ps = 0.f;
      #pragma unroll
      for (int ns = 0; ns < 4; ++ns) { float p = __expf(sv[ns][i] - mnew); sv[ns][i] = p; ps += p; }
      #pragma unroll
      for (int m = 1; m <= 8; m <<= 1) ps += __shfl_xor(ps, m);
      lrun[i] = lrun[i] * fr + ps;
      #pragma unroll
      for (int ds = 0; ds < 4; ++ds) oacc[ds][i] *= fr;
    }
    #pragma unroll
    for (int ns = 0; ns < 4; ++ns)
      #pragma unroll
      for (int i = 0; i < 4; ++i) {
        const int row = w * 16 + lg * 4 + i;
        const int cb = (ns * 16 + lc) * 2;
        *(unsigned short*)((char*)Ps + row * 128 + (cb ^ ((row & 7) << 4))) = f2bf(sv[ns][i]);
      }
    #pragma unroll
    for (int kc = 0; kc < 2; ++kc) {
      bf16x8 pa = read_swz(Ps, w * 16 + lc, kc * 64 + lg * 16);
      #pragma unroll
      for (int ds = 0; ds < 4; ++ds) {
        bf16x8 vb = read_swz(Vts, ds * 16 + lc, kc * 64 + lg * 16);
        oacc[ds] = mfma16(pa, vb, oacc[ds]);
      }
    }
    __syncthreads();   // free Ks/Vts/qds/kds/Ps for next iteration
  }

  // ---- instruct branch ----
  {
    stage_tile_swz(IKg + (size_t)bh * 4096, 64, Ks, w, lane);
    stage_tile_swz(IVtg + (size_t)bh * 4096, 64, Vts, w, lane);
    __syncthreads();
    f32x4 sacc[4];
    #pragma unroll
    for (int ns = 0; ns < 4; ++ns) sacc[ns] = (f32x4){0.f, 0.f, 0.f, 0.f};
    #pragma unroll
    for (int kc = 0; kc < 2; ++kc) {
      bf16x8 qa = read_swz(Qs, w * 16 + lc, kc * 64 + lg * 16);
      #pragma unroll
      for (int ns = 0; ns < 4; ++ns) {
        bf16x8 kb = read_swz(Ks, ns * 16 + lc, kc * 64 + lg * 16);
        sacc[ns] = mfma16(qa, kb, sacc[ns]);
      }
    }
    float sv[4][4], isum[4];
    #pragma unroll
    for (int ns = 0; ns < 4; ++ns) {
      const float mk = imask[b * SIN + ns * 16 + lc];
      #pragma unroll
      for (int i = 0; i < 4; ++i) sv[ns][i] = sacc[ns][i] * scale + mk;
    }
    #pragma unroll
    for (int i = 0; i < 4; ++i) {
      float mt = fmaxf(fmaxf(sv[0][i], sv[1][i]), fmaxf(sv[2][i], sv[3][i]));
      #pragma unroll
      for (int m = 1; m <= 8; m <<= 1) mt = fmaxf(mt, __shfl_xor(mt, m));
      float ps = 0.f;
      #pragma unroll
      for (int ns = 0; ns < 4; ++ns) { float p = __expf(sv[ns][i] - mt); sv[ns][i] = p; ps += p; }
      #pragma unroll
      for (int m = 1; m <= 8; m <<= 1) ps += __shfl_xor(ps, m);
      isum[i] = ps;
    }
    #pragma unroll
    for (int ns = 0; ns < 4; ++ns)
      #pragma unroll
      for (int i = 0; i < 4; ++i) {
        const int row = w * 16 + lg * 4 + i;
        const int cb = (ns * 16 + lc) * 2;
        *(unsigned short*)((char*)Ps + row * 128 + (cb ^ ((row & 7) << 4))) = f2bf(sv[ns][i]);
      }
    f32x4 iacc[4];
    #pragma unroll
    for (int ds = 0; ds < 4; ++ds) iacc[ds] = (f32x4){0.f, 0.f, 0.f, 0.f};
    #pragma unroll
    for (int kc = 0; kc < 2; ++kc) {
      bf16x8 pa = read_swz(Ps, w * 16 + lc, kc * 64 + lg * 16);
      #pragma unroll
      for (int ds = 0; ds < 4; ++ds) {
        bf16x8 vb = read_swz(Vts, ds * 16 + lc, kc * 64 + lg * 16);
        iacc[ds] = mfma16(pa, vb, iacc[ds]);
      }
    }
    const float tg = tanhf(gate[h]);
    #pragma unroll
    for (int ds = 0; ds < 4; ++ds)
      #pragma unroll
      for (int i = 0; i < 4; ++i) {
        const int li = w * 16 + lg * 4 + i;
        const float val = oacc[ds][i] / lrun[i] + tg * (iacc[ds][i] / isum[i]);
        out[(size_t)(b * SEQ + l0 + li) * 1024 + h * 64 + ds * 16 + lc] = val;
      }
  }
}

// ---------------- launch ----------------

extern "C" void kernel_launch(void* const* d_in, const int* in_sizes, int n_in,
                              void* d_out, int out_size, void* d_ws, size_t ws_size,
                              hipStream_t stream) {
  (void)in_sizes; (void)n_in; (void)out_size; (void)ws_size;
  const float* hs    = (const float*)d_in[0];
  const float* ihs   = (const float*)d_in[1];
  const float* mask  = (const float*)d_in[2];
  const float* imask = (const float*)d_in[3];
  const float* Wq    = (const float*)d_in[4];
  const float* bq    = (const float*)d_in[5];
  const float* Wk    = (const float*)d_in[6];
  const float* bk    = (const float*)d_in[7];
  const float* Wv    = (const float*)d_in[8];
  const float* bv    = (const float*)d_in[9];
  const float* de    = (const float*)d_in[10];
  const float* gate  = (const float*)d_in[11];
  float* out = (float*)d_out;

  char* ws = (char*)d_ws;
  size_t off = 0;
  auto alloc = [&](size_t bytes) -> void* {
    void* p = ws + off;
    off += (bytes + 255) & ~(size_t)255;
    return p;
  };
  unsigned short* X    = (unsigned short*)alloc((size_t)4608 * 1024 * 2);
  unsigned short* Wt   = (unsigned short*)alloc((size_t)3072 * 1024 * 2);
  unsigned short* E    = (unsigned short*)alloc((size_t)1024 * 64 * 2);
  unsigned short* Qb   = (unsigned short*)alloc((size_t)8 * 16 * 512 * 64 * 2);
  unsigned short* Kb   = (unsigned short*)alloc((size_t)8 * 16 * 512 * 64 * 2);
  unsigned short* Vtb  = (unsigned short*)alloc((size_t)8 * 16 * 64 * 512 * 2);
  unsigned short* IKb  = (unsigned short*)alloc((size_t)8 * 16 * 64 * 64 * 2);
  unsigned short* IVtb = (unsigned short*)alloc((size_t)8 * 16 * 64 * 64 * 2);

  k_convert_x<<<4608, 256, 0, stream>>>(hs, ihs, X);
  k_convert_w<<<dim3(16, 16, 3), 256, 0, stream>>>(Wq, Wk, Wv, Wt);
  k_convert_e<<<64, 256, 0, stream>>>(de, E);
  k_gemm<<<dim3(24, 36), 256, 0, stream>>>(X, Wt, bq, bk, bv, Qb, Kb, Vtb, IKb, IVtb);
  k_attn<<<dim3(8, 16, 8), 256, 0, stream>>>(Qb, Kb, Vtb, IKb, IVtb, E, mask, imask, gate, out);
}

// Round 4
// 186.201 us; speedup vs baseline: 1.3030x; 1.0030x over previous
//
#include <hip/hip_runtime.h>

#define NH 16
#define DH 64
#define SEQ 512
#define SIN 64
#define NBATCH 8

typedef short bf16x8 __attribute__((ext_vector_type(8)));
typedef float f32x4 __attribute__((ext_vector_type(4)));

__device__ __forceinline__ unsigned short f2bf(float f) {
  union { float f; unsigned u; } v; v.f = f;
  unsigned r = v.u + 0x7FFFu + ((v.u >> 16) & 1u);
  return (unsigned short)(r >> 16);
}
__device__ __forceinline__ float bf2f(unsigned short b) {
  union { unsigned u; float f; } v; v.u = ((unsigned)b) << 16;
  return v.f;
}
__device__ __forceinline__ f32x4 mfma16(bf16x8 a, bf16x8 b, f32x4 c) {
  return __builtin_amdgcn_mfma_f32_16x16x32_bf16(a, b, c, 0, 0, 0);
}
__device__ __forceinline__ void gload_lds16(const unsigned short* g, unsigned short* l) {
  __builtin_amdgcn_global_load_lds((const __attribute__((address_space(1))) void*)g,
                                   (__attribute__((address_space(3))) void*)l, 16, 0, 0);
}

// 64x64 bf16 tile in LDS, logical [64][64], physical byte swizzle
// phys = row*128 + (colbyte ^ ((row&7)<<4)); staged with pre-swizzled global src.
__device__ __forceinline__ void stage_tile_swz(const unsigned short* g, int gstride,
                                               unsigned short* lds, int w, int lane) {
  #pragma unroll
  for (int c = 0; c < 2; ++c) {
    const int row = w * 16 + c * 8 + (lane >> 3);
    const int cb = ((lane & 7) ^ (lane >> 3)) << 4;
    gload_lds16(g + (size_t)row * gstride + (cb >> 1),
                lds + (w * 16 + c * 8) * 64);
  }
}
__device__ __forceinline__ bf16x8 read_swz(const unsigned short* lds, int row, int colbyte) {
  return *(const bf16x8*)((const char*)(lds + row * 64) + (colbyte ^ ((row & 7) << 4)));
}

// ---------------- convert kernels ----------------

__global__ __launch_bounds__(256) void k_convert_x(const float* __restrict__ hs,
                                                   const float* __restrict__ ihs,
                                                   unsigned short* __restrict__ X) {
  int idx = blockIdx.x * 256 + threadIdx.x;
  float4 v;
  if (idx < 1048576) v = ((const float4*)hs)[idx];
  else               v = ((const float4*)ihs)[idx - 1048576];
  ushort4 o; o.x = f2bf(v.x); o.y = f2bf(v.y); o.z = f2bf(v.z); o.w = f2bf(v.w);
  ((ushort4*)X)[idx] = o;
}

__global__ __launch_bounds__(256) void k_convert_e(const float* __restrict__ de,
                                                   unsigned short* __restrict__ E) {
  int idx = blockIdx.x * 256 + threadIdx.x;
  ushort4 o;
  if (idx < 16368) {
    float4 v = ((const float4*)de)[idx];
    o.x = f2bf(v.x); o.y = f2bf(v.y); o.z = f2bf(v.z); o.w = f2bf(v.w);
  } else { o.x = 0; o.y = 0; o.z = 0; o.w = 0; }
  ((ushort4*)E)[idx] = o;
}

__global__ __launch_bounds__(256) void k_convert_w(const float* __restrict__ Wq,
                                                   const float* __restrict__ Wk,
                                                   const float* __restrict__ Wv,
                                                   unsigned short* __restrict__ Wt) {
  __shared__ float t[64][65];
  const float* W = (blockIdx.z == 0) ? Wq : (blockIdx.z == 1) ? Wk : Wv;
  const int n0 = blockIdx.x * 64, k0 = blockIdx.y * 64;
  const int tid = threadIdx.x;
  #pragma unroll
  for (int q = 0; q < 4; ++q) {
    int s = q * 256 + tid;
    int r = s >> 4, c4 = s & 15;
    float4 v = *(const float4*)(W + (size_t)(k0 + r) * 1024 + n0 + c4 * 4);
    t[r][c4 * 4 + 0] = v.x; t[r][c4 * 4 + 1] = v.y;
    t[r][c4 * 4 + 2] = v.z; t[r][c4 * 4 + 3] = v.w;
  }
  __syncthreads();
  #pragma unroll
  for (int q = 0; q < 4; ++q) {
    int s = q * 256 + tid;
    int rn = s >> 4, c4 = s & 15;
    ushort4 o;
    o.x = f2bf(t[c4 * 4 + 0][rn]); o.y = f2bf(t[c4 * 4 + 1][rn]);
    o.z = f2bf(t[c4 * 4 + 2][rn]); o.w = f2bf(t[c4 * 4 + 3][rn]);
    *(ushort4*)(Wt + ((size_t)(blockIdx.z << 10) + n0 + rn) * 1024 + k0 + c4 * 4) = o;
  }
}

// ---------------- fused QKV GEMM (m97-style 128x128, BK=32) ----------------
__global__ __launch_bounds__(256) void k_gemm(const unsigned short* __restrict__ X,
                                              const unsigned short* __restrict__ Wt,
                                              const float* __restrict__ bq,
                                              const float* __restrict__ bk,
                                              const float* __restrict__ bv,
                                              unsigned short* __restrict__ Q,
                                              unsigned short* __restrict__ K,
                                              unsigned short* __restrict__ Vt,
                                              unsigned short* __restrict__ IK,
                                              unsigned short* __restrict__ IVt) {
  __shared__ unsigned short Asm[2][128 * 32];
  __shared__ unsigned short Bsm[2][128 * 32];
  const int tid = threadIdx.x, lane = tid & 63, w = tid >> 6;
  const int lg = lane >> 4, lc = lane & 15;
  const int m0 = blockIdx.y * 128, n0 = blockIdx.x * 128;
  const int wm = (w >> 1) * 64, wn = (w & 1) * 64;

  f32x4 acc[4][4];
  #pragma unroll
  for (int i = 0; i < 4; ++i)
    #pragma unroll
    for (int j = 0; j < 4; ++j) acc[i][j] = (f32x4){0.f, 0.f, 0.f, 0.f};

  #define STAGE(bi, kt)                                                          \
    {                                                                            \
      const int k0_ = (kt) * 32;                                                 \
      _Pragma("unroll")                                                          \
      for (int j_ = 0; j_ < 2; ++j_) {                                           \
        int c_ = w * 128 + j_ * 64 + lane;                                       \
        int r_ = c_ >> 2, cc_ = c_ & 3;                                          \
        gload_lds16(X + (size_t)(m0 + r_) * 1024 + k0_ + cc_ * 8,                \
                    &Asm[bi][(w * 128 + j_ * 64) * 8]);                          \
        gload_lds16(Wt + (size_t)(n0 + r_) * 1024 + k0_ + cc_ * 8,               \
                    &Bsm[bi][(w * 128 + j_ * 64) * 8]);                          \
      }                                                                          \
    }

  STAGE(0, 0);
  int cur = 0;
  for (int kt = 0; kt < 32; ++kt) {
    __syncthreads();
    if (kt + 1 < 32) STAGE(cur ^ 1, kt + 1);
    const unsigned short* A = Asm[cur];
    const unsigned short* B = Bsm[cur];
    bf16x8 af[4], bfr[4];
    #pragma unroll
    for (int i = 0; i < 4; ++i)
      af[i] = *(const bf16x8*)(A + (wm + i * 16 + lc) * 32 + lg * 8);
    #pragma unroll
    for (int j = 0; j < 4; ++j)
      bfr[j] = *(const bf16x8*)(B + (wn + j * 16 + lc) * 32 + lg * 8);
    #pragma unroll
    for (int i = 0; i < 4; ++i)
      #pragma unroll
      for (int j = 0; j < 4; ++j)
        acc[i][j] = mfma16(af[i], bfr[j], acc[i][j]);
    cur ^= 1;
  }
  #undef STAGE

  #pragma unroll
  for (int j = 0; j < 4; ++j) {
    const int gn = n0 + wn + j * 16 + lc;
    const int which = gn >> 10, nn = gn & 1023;
    const int hh = nn >> 6, dd = nn & 63;
    const float bias = (which == 0 ? bq : (which == 1 ? bk : bv))[nn];
    #pragma unroll
    for (int i = 0; i < 4; ++i) {
      #pragma unroll
      for (int ii = 0; ii < 4; ++ii) {
        const int gm = m0 + wm + i * 16 + lg * 4 + ii;
        const unsigned short o = f2bf(acc[i][j][ii] + bias);
        if (gm < 4096) {
          const int bb = gm >> 9, ss = gm & 511;
          if (which == 0)      Q[(((size_t)(bb * NH + hh) * 512 + ss) << 6) + dd] = o;
          else if (which == 1) K[(((size_t)(bb * NH + hh) * 512 + ss) << 6) + dd] = o;
          else                 Vt[((size_t)(bb * NH + hh) * 64 + dd) * 512 + ss] = o;
        } else {
          const int mi = gm - 4096, bb = mi >> 6, si = mi & 63;
          if (which == 1)      IK[((size_t)(bb * NH + hh) * 64 + si) * 64 + dd] = o;
          else if (which == 2) IVt[((size_t)(bb * NH + hh) * 64 + dd) * 64 + si] = o;
        }
      }
    }
  }
}

// ---------------- bias tile kernel ----------------
// Bias[bh][lt][rt][li][ri] = q_{l0+li}.E[j] + k_{r0+ri}.E[j],  j = l-r+511.
// Per block: qd/kd MFMAs vs the 128-row E window, sheared LDS combine, coalesced store.
__global__ __launch_bounds__(256) void k_bias(const unsigned short* __restrict__ Qg,
                                              const unsigned short* __restrict__ Kg,
                                              const unsigned short* __restrict__ Eg,
                                              unsigned short* __restrict__ Bias) {
  const int rt = blockIdx.x, lt = blockIdx.y, bh = blockIdx.z;
  const int l0 = lt * 64, r0 = rt * 64;
  const int p0 = l0 - r0 + 448;
  const int tid = threadIdx.x, lane = tid & 63, w = tid >> 6;
  const int lg = lane >> 4, lc = lane & 15;
  const int ubase = w * 32;

  __shared__ unsigned short Qs[64 * 64], Ks[64 * 64];
  __shared__ unsigned short qds[64 * 76], kds[64 * 76];

  stage_tile_swz(Qg + ((size_t)(bh * 512 + l0)) * 64, 64, Qs, w, lane);
  stage_tile_swz(Kg + ((size_t)(bh * 512 + r0)) * 64, 64, Ks, w, lane);

  bf16x8 eb[2][2];
  #pragma unroll
  for (int ns = 0; ns < 2; ++ns) {
    const int u = ubase + ns * 16 + lc;
    const unsigned short* ep = Eg + (size_t)(p0 + u) * 64 + lg * 8;
    eb[ns][0] = *(const bf16x8*)(ep);
    eb[ns][1] = *(const bf16x8*)(ep + 32);
  }
  __syncthreads();

  {
    f32x4 da[4][2];
    #pragma unroll
    for (int ms = 0; ms < 4; ++ms) { da[ms][0] = (f32x4){0,0,0,0}; da[ms][1] = (f32x4){0,0,0,0}; }
    #pragma unroll
    for (int kc = 0; kc < 2; ++kc)
      #pragma unroll
      for (int ms = 0; ms < 4; ++ms) {
        bf16x8 a = read_swz(Qs, ms * 16 + lc, kc * 64 + lg * 16);
        da[ms][0] = mfma16(a, eb[0][kc], da[ms][0]);
        da[ms][1] = mfma16(a, eb[1][kc], da[ms][1]);
      }
    #pragma unroll
    for (int ms = 0; ms < 4; ++ms)
      #pragma unroll
      for (int ns = 0; ns < 2; ++ns) {
        const int u = ubase + ns * 16 + lc;
        #pragma unroll
        for (int i = 0; i < 4; ++i) {
          const int l = ms * 16 + lg * 4 + i;
          const int ri = l - u + 63;
          if ((unsigned)ri < 64u) qds[l * 76 + ri] = f2bf(da[ms][ns][i]);
        }
      }
    #pragma unroll
    for (int ms = 0; ms < 4; ++ms) { da[ms][0] = (f32x4){0,0,0,0}; da[ms][1] = (f32x4){0,0,0,0}; }
    #pragma unroll
    for (int kc = 0; kc < 2; ++kc)
      #pragma unroll
      for (int ms = 0; ms < 4; ++ms) {
        bf16x8 a = read_swz(Ks, ms * 16 + lc, kc * 64 + lg * 16);
        da[ms][0] = mfma16(a, eb[0][kc], da[ms][0]);
        da[ms][1] = mfma16(a, eb[1][kc], da[ms][1]);
      }
    #pragma unroll
    for (int ms = 0; ms < 4; ++ms)
      #pragma unroll
      for (int ns = 0; ns < 2; ++ns) {
        const int u = ubase + ns * 16 + lc;
        #pragma unroll
        for (int i = 0; i < 4; ++i) {
          const int r = ms * 16 + lg * 4 + i;
          const int li = r + u - 63;
          if ((unsigned)li < 64u) kds[r * 76 + li] = f2bf(da[ms][ns][i]);
        }
      }
  }
  __syncthreads();

  // combine + coalesced write: thread -> row li = tid>>2, 16 cols at ri0
  {
    const int li = tid >> 2, ri0 = (tid & 3) * 16;
    unsigned short ob[16];
    #pragma unroll
    for (int t = 0; t < 16; ++t) {
      const int ri = ri0 + t;
      ob[t] = f2bf(bf2f(qds[li * 76 + ri]) + bf2f(kds[ri * 76 + li]));
    }
    unsigned short* dst = Bias + (((size_t)(bh * 64 + lt * 8 + rt)) << 12) + li * 64 + ri0;
    *(uint4*)(dst)     = *(uint4*)&ob[0];
    *(uint4*)(dst + 8) = *(uint4*)&ob[8];
  }
}

// ---------------- fused attention (flash) ----------------
// Per iter: stage K/V (swz) + pre-sheared bias tile (xor-swizzled); QK^T + bias
// + online softmax + PV.  LDS = 32 KB -> 4 blocks/CU; grid 1024 = 4/CU.
__global__ __launch_bounds__(256) void k_attn(const unsigned short* __restrict__ Qg,
                                              const unsigned short* __restrict__ Kg,
                                              const unsigned short* __restrict__ Vtg,
                                              const unsigned short* __restrict__ IKg,
                                              const unsigned short* __restrict__ IVtg,
                                              const unsigned short* __restrict__ Bias,
                                              const float* __restrict__ mask,
                                              const float* __restrict__ imask,
                                              const float* __restrict__ gate,
                                              float* __restrict__ out) {
  const int lt = blockIdx.x, h = blockIdx.y, b = blockIdx.z;
  const int l0 = lt * 64;
  const int tid = threadIdx.x;
  const int lane = tid & 63, w = tid >> 6;
  const int lg = lane >> 4, lc = lane & 15;
  const int bh = b * NH + h;

  __shared__ unsigned short Ks[64 * 64];   // swizzled
  __shared__ unsigned short Vts[64 * 64];  // swizzled
  __shared__ unsigned short Bs[64 * 64];   // xor-swizzled bias tile
  __shared__ unsigned short Ps[64 * 64];   // swizzled

  // Q fragments in registers (wave w owns q-rows [16w,16w+16))
  bf16x8 qa[2];
  {
    const unsigned short* qrow = Qg + ((size_t)(bh * 512 + l0 + w * 16 + lc)) * 64;
    qa[0] = *(const bf16x8*)(qrow + lg * 8);
    qa[1] = *(const bf16x8*)(qrow + 32 + lg * 8);
  }

  f32x4 oacc[4];
  #pragma unroll
  for (int i = 0; i < 4; ++i) oacc[i] = (f32x4){0.f, 0.f, 0.f, 0.f};
  float mrun[4], lrun[4];
  #pragma unroll
  for (int i = 0; i < 4; ++i) { mrun[i] = -3.0e38f; lrun[i] = 0.f; }
  const float scale = 0.125f;

  for (int rt = 0; rt < 8; ++rt) {
    const int r0 = rt * 64;
    stage_tile_swz(Kg + ((size_t)(bh * 512 + r0)) * 64, 64, Ks, w, lane);
    stage_tile_swz(Vtg + (size_t)bh * 64 * 512 + r0, 512, Vts, w, lane);
    {
      const unsigned short* bt = Bias + (((size_t)(bh * 64 + lt * 8 + rt)) << 12);
      #pragma unroll
      for (int q = 0; q < 2; ++q) {
        int ch = q * 256 + tid;
        int row = ch >> 3, c8 = ch & 7;
        gload_lds16(bt + row * 64 + ((c8 ^ (((row >> 2) & 3) << 1)) << 3),
                    Bs + (q * 256 + w * 64) * 8);
      }
    }
    __syncthreads();

    f32x4 sacc[4];
    #pragma unroll
    for (int ns = 0; ns < 4; ++ns) sacc[ns] = (f32x4){0.f, 0.f, 0.f, 0.f};
    #pragma unroll
    for (int kc = 0; kc < 2; ++kc)
      #pragma unroll
      for (int ns = 0; ns < 4; ++ns) {
        bf16x8 kb = read_swz(Ks, ns * 16 + lc, kc * 64 + lg * 16);
        sacc[ns] = mfma16(qa[kc], kb, sacc[ns]);
      }
    float sv[4][4];
    #pragma unroll
    for (int ns = 0; ns < 4; ++ns) {
      const float mk = mask[b * SEQ + r0 + ns * 16 + lc];
      #pragma unroll
      for (int i = 0; i < 4; ++i) {
        const int li = w * 16 + lg * 4 + i;
        const float bval = bf2f(*(const unsigned short*)
            ((const char*)Bs + li * 128 + ((ns * 32 + lc * 2) ^ (lg << 5))));
        sv[ns][i] = (sacc[ns][i] + bval) * scale + mk;
      }
    }
    #pragma unroll
    for (int i = 0; i < 4; ++i) {
      float mt = fmaxf(fmaxf(sv[0][i], sv[1][i]), fmaxf(sv[2][i], sv[3][i]));
      #pragma unroll
      for (int m = 1; m <= 8; m <<= 1) mt = fmaxf(mt, __shfl_xor(mt, m));
      const float mnew = fmaxf(mrun[i], mt);
      const float fr = __expf(mrun[i] - mnew);
      mrun[i] = mnew;
      float ps = 0.f;
      #pragma unroll
      for (int ns = 0; ns < 4; ++ns) { float p = __expf(sv[ns][i] - mnew); sv[ns][i] = p; ps += p; }
      #pragma unroll
      for (int m = 1; m <= 8; m <<= 1) ps += __shfl_xor(ps, m);
      lrun[i] = lrun[i] * fr + ps;
      #pragma unroll
      for (int ds = 0; ds < 4; ++ds) oacc[ds][i] *= fr;
    }
    #pragma unroll
    for (int ns = 0; ns < 4; ++ns)
      #pragma unroll
      for (int i = 0; i < 4; ++i) {
        const int row = w * 16 + lg * 4 + i;
        const int cb = (ns * 16 + lc) * 2;
        *(unsigned short*)((char*)Ps + row * 128 + (cb ^ ((row & 7) << 4))) = f2bf(sv[ns][i]);
      }
    #pragma unroll
    for (int kc = 0; kc < 2; ++kc) {
      bf16x8 pa = read_swz(Ps, w * 16 + lc, kc * 64 + lg * 16);
      #pragma unroll
      for (int ds = 0; ds < 4; ++ds) {
        bf16x8 vb = read_swz(Vts, ds * 16 + lc, kc * 64 + lg * 16);
        oacc[ds] = mfma16(pa, vb, oacc[ds]);
      }
    }
    __syncthreads();
  }

  // ---- instruct branch ----
  {
    stage_tile_swz(IKg + (size_t)bh * 4096, 64, Ks, w, lane);
    stage_tile_swz(IVtg + (size_t)bh * 4096, 64, Vts, w, lane);
    __syncthreads();
    f32x4 sacc[4];
    #pragma unroll
    for (int ns = 0; ns < 4; ++ns) sacc[ns] = (f32x4){0.f, 0.f, 0.f, 0.f};
    #pragma unroll
    for (int kc = 0; kc < 2; ++kc)
      #pragma unroll
      for (int ns = 0; ns < 4; ++ns) {
        bf16x8 kb = read_swz(Ks, ns * 16 + lc, kc * 64 + lg * 16);
        sacc[ns] = mfma16(qa[kc], kb, sacc[ns]);
      }
    float sv[4][4], isum[4];
    #pragma unroll
    for (int ns = 0; ns < 4; ++ns) {
      const float mk = imask[b * SIN + ns * 16 + lc];
      #pragma unroll
      for (int i = 0; i < 4; ++i) sv[ns][i] = sacc[ns][i] * scale + mk;
    }
    #pragma unroll
    for (int i = 0; i < 4; ++i) {
      float mt = fmaxf(fmaxf(sv[0][i], sv[1][i]), fmaxf(sv[2][i], sv[3][i]));
      #pragma unroll
      for (int m = 1; m <= 8; m <<= 1) mt = fmaxf(mt, __shfl_xor(mt, m));
      float ps = 0.f;
      #pragma unroll
      for (int ns = 0; ns < 4; ++ns) { float p = __expf(sv[ns][i] - mt); sv[ns][i] = p; ps += p; }
      #pragma unroll
      for (int m = 1; m <= 8; m <<= 1) ps += __shfl_xor(ps, m);
      isum[i] = ps;
    }
    #pragma unroll
    for (int ns = 0; ns < 4; ++ns)
      #pragma unroll
      for (int i = 0; i < 4; ++i) {
        const int row = w * 16 + lg * 4 + i;
        const int cb = (ns * 16 + lc) * 2;
        *(unsigned short*)((char*)Ps + row * 128 + (cb ^ ((row & 7) << 4))) = f2bf(sv[ns][i]);
      }
    f32x4 iacc[4];
    #pragma unroll
    for (int ds = 0; ds < 4; ++ds) iacc[ds] = (f32x4){0.f, 0.f, 0.f, 0.f};
    #pragma unroll
    for (int kc = 0; kc < 2; ++kc) {
      bf16x8 pa = read_swz(Ps, w * 16 + lc, kc * 64 + lg * 16);
      #pragma unroll
      for (int ds = 0; ds < 4; ++ds) {
        bf16x8 vb = read_swz(Vts, ds * 16 + lc, kc * 64 + lg * 16);
        iacc[ds] = mfma16(pa, vb, iacc[ds]);
      }
    }
    const float tg = tanhf(gate[h]);
    #pragma unroll
    for (int ds = 0; ds < 4; ++ds)
      #pragma unroll
      for (int i = 0; i < 4; ++i) {
        const int li = w * 16 + lg * 4 + i;
        const float val = oacc[ds][i] / lrun[i] + tg * (iacc[ds][i] / isum[i]);
        out[(size_t)(b * SEQ + l0 + li) * 1024 + h * 64 + ds * 16 + lc] = val;
      }
  }
}

// ---------------- launch ----------------

extern "C" void kernel_launch(void* const* d_in, const int* in_sizes, int n_in,
                              void* d_out, int out_size, void* d_ws, size_t ws_size,
                              hipStream_t stream) {
  (void)in_sizes; (void)n_in; (void)out_size; (void)ws_size;
  const float* hs    = (const float*)d_in[0];
  const float* ihs   = (const float*)d_in[1];
  const float* mask  = (const float*)d_in[2];
  const float* imask = (const float*)d_in[3];
  const float* Wq    = (const float*)d_in[4];
  const float* bq    = (const float*)d_in[5];
  const float* Wk    = (const float*)d_in[6];
  const float* bk    = (const float*)d_in[7];
  const float* Wv    = (const float*)d_in[8];
  const float* bv    = (const float*)d_in[9];
  const float* de    = (const float*)d_in[10];
  const float* gate  = (const float*)d_in[11];
  float* out = (float*)d_out;

  char* ws = (char*)d_ws;
  size_t off = 0;
  auto alloc = [&](size_t bytes) -> void* {
    void* p = ws + off;
    off += (bytes + 255) & ~(size_t)255;
    return p;
  };
  unsigned short* X    = (unsigned short*)alloc((size_t)4608 * 1024 * 2);
  unsigned short* Wt   = (unsigned short*)alloc((size_t)3072 * 1024 * 2);
  unsigned short* E    = (unsigned short*)alloc((size_t)1024 * 64 * 2);
  unsigned short* Qb   = (unsigned short*)alloc((size_t)8 * 16 * 512 * 64 * 2);
  unsigned short* Kb   = (unsigned short*)alloc((size_t)8 * 16 * 512 * 64 * 2);
  unsigned short* Vtb  = (unsigned short*)alloc((size_t)8 * 16 * 64 * 512 * 2);
  unsigned short* IKb  = (unsigned short*)alloc((size_t)8 * 16 * 64 * 64 * 2);
  unsigned short* IVtb = (unsigned short*)alloc((size_t)8 * 16 * 64 * 64 * 2);
  unsigned short* Bias = (unsigned short*)alloc((size_t)128 * 64 * 4096 * 2);  // 64 MiB

  k_convert_x<<<4608, 256, 0, stream>>>(hs, ihs, X);
  k_convert_w<<<dim3(16, 16, 3), 256, 0, stream>>>(Wq, Wk, Wv, Wt);
  k_convert_e<<<64, 256, 0, stream>>>(de, E);
  k_gemm<<<dim3(24, 36), 256, 0, stream>>>(X, Wt, bq, bk, bv, Qb, Kb, Vtb, IKb, IVtb);
  k_bias<<<dim3(8, 8, 128), 256, 0, stream>>>(Qb, Kb, E, Bias);
  k_attn<<<dim3(8, 16, 8), 256, 0, stream>>>(Qb, Kb, Vtb, IKb, IVtb, Bias, mask, imask, gate, out);
}

// Round 7
// 169.183 us; speedup vs baseline: 1.4340x; 1.1006x over previous
//
#include <hip/hip_runtime.h>

#define NH 16
#define DH 64
#define SEQ 512
#define SIN 64
#define NBATCH 8

typedef short bf16x8 __attribute__((ext_vector_type(8)));
typedef float f32x4 __attribute__((ext_vector_type(4)));

__device__ __forceinline__ unsigned short f2bf(float f) {
  union { float f; unsigned u; } v; v.f = f;
  unsigned r = v.u + 0x7FFFu + ((v.u >> 16) & 1u);
  return (unsigned short)(r >> 16);
}
__device__ __forceinline__ float bf2f(unsigned short b) {
  union { unsigned u; float f; } v; v.u = ((unsigned)b) << 16;
  return v.f;
}
__device__ __forceinline__ f32x4 mfma16(bf16x8 a, bf16x8 b, f32x4 c) {
  return __builtin_amdgcn_mfma_f32_16x16x32_bf16(a, b, c, 0, 0, 0);
}
__device__ __forceinline__ void gload_lds16(const unsigned short* g, unsigned short* l) {
  __builtin_amdgcn_global_load_lds((const __attribute__((address_space(1))) void*)g,
                                   (__attribute__((address_space(3))) void*)l, 16, 0, 0);
}

// 64x64 bf16 tile in LDS, logical [64][64], physical byte swizzle
// phys = row*128 + (colbyte ^ ((row&7)<<4)); staged with pre-swizzled global src.
__device__ __forceinline__ void stage_tile_swz(const unsigned short* g, int gstride,
                                               unsigned short* lds, int w, int lane) {
  #pragma unroll
  for (int c = 0; c < 2; ++c) {
    const int row = w * 16 + c * 8 + (lane >> 3);
    const int cb = ((lane & 7) ^ (lane >> 3)) << 4;
    gload_lds16(g + (size_t)row * gstride + (cb >> 1),
                lds + (w * 16 + c * 8) * 64);
  }
}
__device__ __forceinline__ bf16x8 read_swz(const unsigned short* lds, int row, int colbyte) {
  return *(const bf16x8*)((const char*)(lds + row * 64) + (colbyte ^ ((row & 7) << 4)));
}

// ---------------- convert kernels ----------------

__global__ __launch_bounds__(256) void k_convert_x(const float* __restrict__ hs,
                                                   const float* __restrict__ ihs,
                                                   unsigned short* __restrict__ X) {
  int idx = blockIdx.x * 256 + threadIdx.x;
  float4 v;
  if (idx < 1048576) v = ((const float4*)hs)[idx];
  else               v = ((const float4*)ihs)[idx - 1048576];
  ushort4 o; o.x = f2bf(v.x); o.y = f2bf(v.y); o.z = f2bf(v.z); o.w = f2bf(v.w);
  ((ushort4*)X)[idx] = o;
}

__global__ __launch_bounds__(256) void k_convert_e(const float* __restrict__ de,
                                                   unsigned short* __restrict__ E) {
  int idx = blockIdx.x * 256 + threadIdx.x;
  ushort4 o;
  if (idx < 16368) {
    float4 v = ((const float4*)de)[idx];
    o.x = f2bf(v.x); o.y = f2bf(v.y); o.z = f2bf(v.z); o.w = f2bf(v.w);
  } else { o.x = 0; o.y = 0; o.z = 0; o.w = 0; }
  ((ushort4*)E)[idx] = o;
}

__global__ __launch_bounds__(256) void k_convert_w(const float* __restrict__ Wq,
                                                   const float* __restrict__ Wk,
                                                   const float* __restrict__ Wv,
                                                   unsigned short* __restrict__ Wt) {
  __shared__ float t[64][65];
  const float* W = (blockIdx.z == 0) ? Wq : (blockIdx.z == 1) ? Wk : Wv;
  const int n0 = blockIdx.x * 64, k0 = blockIdx.y * 64;
  const int tid = threadIdx.x;
  #pragma unroll
  for (int q = 0; q < 4; ++q) {
    int s = q * 256 + tid;
    int r = s >> 4, c4 = s & 15;
    float4 v = *(const float4*)(W + (size_t)(k0 + r) * 1024 + n0 + c4 * 4);
    t[r][c4 * 4 + 0] = v.x; t[r][c4 * 4 + 1] = v.y;
    t[r][c4 * 4 + 2] = v.z; t[r][c4 * 4 + 3] = v.w;
  }
  __syncthreads();
  #pragma unroll
  for (int q = 0; q < 4; ++q) {
    int s = q * 256 + tid;
    int rn = s >> 4, c4 = s & 15;
    ushort4 o;
    o.x = f2bf(t[c4 * 4 + 0][rn]); o.y = f2bf(t[c4 * 4 + 1][rn]);
    o.z = f2bf(t[c4 * 4 + 2][rn]); o.w = f2bf(t[c4 * 4 + 3][rn]);
    *(ushort4*)(Wt + ((size_t)(blockIdx.z << 10) + n0 + rn) * 1024 + k0 + c4 * 4) = o;
  }
}

// ---------------- fused QKV GEMM (128x128, BK=32) ----------------
// Hoisted staging pointers; epilogue restaged through LDS for wide stores.
__global__ __launch_bounds__(256) void k_gemm(const unsigned short* __restrict__ X,
                                              const unsigned short* __restrict__ Wt,
                                              const float* __restrict__ bq,
                                              const float* __restrict__ bk,
                                              const float* __restrict__ bv,
                                              unsigned short* __restrict__ Q,
                                              unsigned short* __restrict__ K,
                                              unsigned short* __restrict__ Vt,
                                              unsigned short* __restrict__ IK,
                                              unsigned short* __restrict__ IVt) {
  __shared__ unsigned short smem[16384];   // A: [bi]*4096, B: 8192+[bi]*4096; epilogue: 128x128 C
  const int tid = threadIdx.x, lane = tid & 63, w = tid >> 6;
  const int lg = lane >> 4, lc = lane & 15;
  const int m0 = blockIdx.y * 128, n0 = blockIdx.x * 128;
  const int wm = (w >> 1) * 64, wn = (w & 1) * 64;
  const int which = n0 >> 10;              // block-uniform (1024 % 128 == 0)
  const int h0 = (n0 & 1023) >> 6;
  const float* barr = (which == 0) ? bq : (which == 1) ? bk : bv;

  f32x4 acc[4][4];
  #pragma unroll
  for (int i = 0; i < 4; ++i)
    #pragma unroll
    for (int j = 0; j < 4; ++j) acc[i][j] = (f32x4){0.f, 0.f, 0.f, 0.f};

  // hoisted staging pointers (advance by 32 elems per K-step)
  const int ca = w * 128 + lane, cb2 = ca + 64;
  const unsigned short* ap0 = X  + (size_t)(m0 + (ca  >> 2)) * 1024 + (ca  & 3) * 8;
  const unsigned short* ap1 = X  + (size_t)(m0 + (cb2 >> 2)) * 1024 + (cb2 & 3) * 8;
  const unsigned short* bp0 = Wt + (size_t)(n0 + (ca  >> 2)) * 1024 + (ca  & 3) * 8;
  const unsigned short* bp1 = Wt + (size_t)(n0 + (cb2 >> 2)) * 1024 + (cb2 & 3) * 8;

  #define STAGE(bi)                                                   \
    {                                                                 \
      gload_lds16(ap0, smem + (bi) * 4096 + (w * 128) * 8);           \
      gload_lds16(ap1, smem + (bi) * 4096 + (w * 128 + 64) * 8);      \
      gload_lds16(bp0, smem + 8192 + (bi) * 4096 + (w * 128) * 8);    \
      gload_lds16(bp1, smem + 8192 + (bi) * 4096 + (w * 128 + 64) * 8); \
      ap0 += 32; ap1 += 32; bp0 += 32; bp1 += 32;                     \
    }

  STAGE(0);
  int cur = 0;
  for (int kt = 0; kt < 32; ++kt) {
    __syncthreads();
    if (kt + 1 < 32) STAGE(cur ^ 1);
    const unsigned short* A = smem + cur * 4096;
    const unsigned short* B = smem + 8192 + cur * 4096;
    bf16x8 af[4], bfr[4];
    #pragma unroll
    for (int i = 0; i < 4; ++i)
      af[i] = *(const bf16x8*)(A + (wm + i * 16 + lc) * 32 + lg * 8);
    #pragma unroll
    for (int j = 0; j < 4; ++j)
      bfr[j] = *(const bf16x8*)(B + (wn + j * 16 + lc) * 32 + lg * 8);
    #pragma unroll
    for (int i = 0; i < 4; ++i)
      #pragma unroll
      for (int j = 0; j < 4; ++j)
        acc[i][j] = mfma16(af[i], bfr[j], acc[i][j]);
    cur ^= 1;
  }
  #undef STAGE

  // ---- epilogue: restage C through LDS (swizzled), wide coalesced stores ----
  __syncthreads();   // all fragment reads done; smem reusable
  {
    char* Cs = (char*)smem;
    #pragma unroll
    for (int j = 0; j < 4; ++j) {
      const float bias = barr[(n0 & 1023) + wn + j * 16 + lc];
      #pragma unroll
      for (int i = 0; i < 4; ++i)
        #pragma unroll
        for (int ii = 0; ii < 4; ++ii) {
          int row = wm + i * 16 + lg * 4 + ii;
          int col = wn + j * 16 + lc;
          if (which == 2) { int t = row; row = col; col = t; }  // V: store transposed
          *(unsigned short*)(Cs + row * 256 + ((col * 2) ^ ((row & 7) << 4))) =
              f2bf(acc[i][j][ii] + bias);
        }
    }
  }
  __syncthreads();
  {
    const char* Cs = (const char*)smem;
    const int row = tid >> 1, half = tid & 1;  // row = tile-row (Q/K) or d-index (V)
    uint4 cvec[8];
    #pragma unroll
    for (int c8 = 0; c8 < 8; ++c8) {
      const int colb = half * 128 + c8 * 16;
      cvec[c8] = *(const uint4*)(Cs + row * 256 + (colb ^ ((row & 7) << 4)));
    }
    unsigned short* dst = nullptr;
    if (which != 2) {
      const int gm = m0 + row, hh = h0 + half;
      if (gm < 4096) {
        const int bb = gm >> 9, ss = gm & 511;
        unsigned short* base = (which == 0) ? Q : K;
        dst = base + (((size_t)(bb * NH + hh) * 512 + ss) << 6);
      } else if (which == 1) {
        const int mi = gm - 4096, bb = mi >> 6, si = mi & 63;
        dst = IK + (((size_t)(bb * NH + hh) * 64 + si) << 6);
      }
    } else {
      const int dd = row, hh = h0 + (dd >> 6), ddl = dd & 63;
      if (m0 < 4096) {
        const int bb = m0 >> 9, ss0 = (m0 & 511) + half * 64;
        dst = Vt + ((size_t)(bb * NH + hh) * 64 + ddl) * 512 + ss0;
      } else {
        const int mi0 = m0 - 4096 + half * 64, bb = mi0 >> 6;
        dst = IVt + (((size_t)(bb * NH + hh) * 64 + ddl) << 6);
      }
    }
    if (dst) {
      #pragma unroll
      for (int c8 = 0; c8 < 8; ++c8)
        *(uint4*)(dst + c8 * 8) = cvec[c8];
    }
  }
}

// ---------------- bias tile kernel ----------------
// Bias[bh][lt][rt][li][ri] = q_{l0+li}.E[j] + k_{r0+ri}.E[j],  j = l-r+511.
__global__ __launch_bounds__(256) void k_bias(const unsigned short* __restrict__ Qg,
                                              const unsigned short* __restrict__ Kg,
                                              const unsigned short* __restrict__ Eg,
                                              unsigned short* __restrict__ Bias) {
  const int rt = blockIdx.x, lt = blockIdx.y, bh = blockIdx.z;
  const int l0 = lt * 64, r0 = rt * 64;
  const int p0 = l0 - r0 + 448;
  const int tid = threadIdx.x, lane = tid & 63, w = tid >> 6;
  const int lg = lane >> 4, lc = lane & 15;
  const int ubase = w * 32;

  __shared__ unsigned short Qs[64 * 64], Ks[64 * 64];
  __shared__ unsigned short qds[64 * 76], kds[64 * 76];

  stage_tile_swz(Qg + ((size_t)(bh * 512 + l0)) * 64, 64, Qs, w, lane);
  stage_tile_swz(Kg + ((size_t)(bh * 512 + r0)) * 64, 64, Ks, w, lane);

  bf16x8 eb[2][2];
  #pragma unroll
  for (int ns = 0; ns < 2; ++ns) {
    const int u = ubase + ns * 16 + lc;
    const unsigned short* ep = Eg + (size_t)(p0 + u) * 64 + lg * 8;
    eb[ns][0] = *(const bf16x8*)(ep);
    eb[ns][1] = *(const bf16x8*)(ep + 32);
  }
  __syncthreads();

  {
    f32x4 da[4][2];
    #pragma unroll
    for (int ms = 0; ms < 4; ++ms) { da[ms][0] = (f32x4){0,0,0,0}; da[ms][1] = (f32x4){0,0,0,0}; }
    #pragma unroll
    for (int kc = 0; kc < 2; ++kc)
      #pragma unroll
      for (int ms = 0; ms < 4; ++ms) {
        bf16x8 a = read_swz(Qs, ms * 16 + lc, kc * 64 + lg * 16);
        da[ms][0] = mfma16(a, eb[0][kc], da[ms][0]);
        da[ms][1] = mfma16(a, eb[1][kc], da[ms][1]);
      }
    #pragma unroll
    for (int ms = 0; ms < 4; ++ms)
      #pragma unroll
      for (int ns = 0; ns < 2; ++ns) {
        const int u = ubase + ns * 16 + lc;
        #pragma unroll
        for (int i = 0; i < 4; ++i) {
          const int l = ms * 16 + lg * 4 + i;
          const int ri = l - u + 63;
          if ((unsigned)ri < 64u) qds[l * 76 + ri] = f2bf(da[ms][ns][i]);
        }
      }
    #pragma unroll
    for (int ms = 0; ms < 4; ++ms) { da[ms][0] = (f32x4){0,0,0,0}; da[ms][1] = (f32x4){0,0,0,0}; }
    #pragma unroll
    for (int kc = 0; kc < 2; ++kc)
      #pragma unroll
      for (int ms = 0; ms < 4; ++ms) {
        bf16x8 a = read_swz(Ks, ms * 16 + lc, kc * 64 + lg * 16);
        da[ms][0] = mfma16(a, eb[0][kc], da[ms][0]);
        da[ms][1] = mfma16(a, eb[1][kc], da[ms][1]);
      }
    #pragma unroll
    for (int ms = 0; ms < 4; ++ms)
      #pragma unroll
      for (int ns = 0; ns < 2; ++ns) {
        const int u = ubase + ns * 16 + lc;
        #pragma unroll
        for (int i = 0; i < 4; ++i) {
          const int r = ms * 16 + lg * 4 + i;
          const int li = r + u - 63;
          if ((unsigned)li < 64u) kds[r * 76 + li] = f2bf(da[ms][ns][i]);
        }
      }
  }
  __syncthreads();

  {
    const int li = tid >> 2, ri0 = (tid & 3) * 16;
    unsigned short ob[16];
    #pragma unroll
    for (int t = 0; t < 16; ++t) {
      const int ri = ri0 + t;
      ob[t] = f2bf(bf2f(qds[li * 76 + ri]) + bf2f(kds[ri * 76 + li]));
    }
    unsigned short* dst = Bias + (((size_t)(bh * 64 + lt * 8 + rt)) << 12) + li * 64 + ri0;
    *(uint4*)(dst)     = *(uint4*)&ob[0];
    *(uint4*)(dst + 8) = *(uint4*)&ob[8];
  }
}

// ---------------- fused attention (flash) ----------------
__global__ __launch_bounds__(256) void k_attn(const unsigned short* __restrict__ Qg,
                                              const unsigned short* __restrict__ Kg,
                                              const unsigned short* __restrict__ Vtg,
                                              const unsigned short* __restrict__ IKg,
                                              const unsigned short* __restrict__ IVtg,
                                              const unsigned short* __restrict__ Bias,
                                              const float* __restrict__ mask,
                                              const float* __restrict__ imask,
                                              const float* __restrict__ gate,
                                              float* __restrict__ out) {
  const int lt = blockIdx.x, h = blockIdx.y, b = blockIdx.z;
  const int l0 = lt * 64;
  const int tid = threadIdx.x;
  const int lane = tid & 63, w = tid >> 6;
  const int lg = lane >> 4, lc = lane & 15;
  const int bh = b * NH + h;

  __shared__ unsigned short Ks[64 * 64];
  __shared__ unsigned short Vts[64 * 64];
  __shared__ unsigned short Bs[64 * 64];
  __shared__ unsigned short Ps[64 * 64];

  bf16x8 qa[2];
  {
    const unsigned short* qrow = Qg + ((size_t)(bh * 512 + l0 + w * 16 + lc)) * 64;
    qa[0] = *(const bf16x8*)(qrow + lg * 8);
    qa[1] = *(const bf16x8*)(qrow + 32 + lg * 8);
  }

  f32x4 oacc[4];
  #pragma unroll
  for (int i = 0; i < 4; ++i) oacc[i] = (f32x4){0.f, 0.f, 0.f, 0.f};
  float mrun[4], lrun[4];
  #pragma unroll
  for (int i = 0; i < 4; ++i) { mrun[i] = -3.0e38f; lrun[i] = 0.f; }
  const float scale = 0.125f;

  for (int rt = 0; rt < 8; ++rt) {
    const int r0 = rt * 64;
    stage_tile_swz(Kg + ((size_t)(bh * 512 + r0)) * 64, 64, Ks, w, lane);
    stage_tile_swz(Vtg + (size_t)bh * 64 * 512 + r0, 512, Vts, w, lane);
    {
      const unsigned short* bt = Bias + (((size_t)(bh * 64 + lt * 8 + rt)) << 12);
      #pragma unroll
      for (int q = 0; q < 2; ++q) {
        int ch = q * 256 + tid;
        int row = ch >> 3, c8 = ch & 7;
        gload_lds16(bt + row * 64 + ((c8 ^ (((row >> 2) & 3) << 1)) << 3),
                    Bs + (q * 256 + w * 64) * 8);
      }
    }
    __syncthreads();

    f32x4 sacc[4];
    #pragma unroll
    for (int ns = 0; ns < 4; ++ns) sacc[ns] = (f32x4){0.f, 0.f, 0.f, 0.f};
    #pragma unroll
    for (int kc = 0; kc < 2; ++kc)
      #pragma unroll
      for (int ns = 0; ns < 4; ++ns) {
        bf16x8 kb = read_swz(Ks, ns * 16 + lc, kc * 64 + lg * 16);
        sacc[ns] = mfma16(qa[kc], kb, sacc[ns]);
      }
    float sv[4][4];
    #pragma unroll
    for (int ns = 0; ns < 4; ++ns) {
      const float mk = mask[b * SEQ + r0 + ns * 16 + lc];
      #pragma unroll
      for (int i = 0; i < 4; ++i) {
        const int li = w * 16 + lg * 4 + i;
        const float bval = bf2f(*(const unsigned short*)
            ((const char*)Bs + li * 128 + ((ns * 32 + lc * 2) ^ (lg << 5))));
        sv[ns][i] = (sacc[ns][i] + bval) * scale + mk;
      }
    }
    #pragma unroll
    for (int i = 0; i < 4; ++i) {
      float mt = fmaxf(fmaxf(sv[0][i], sv[1][i]), fmaxf(sv[2][i], sv[3][i]));
      #pragma unroll
      for (int m = 1; m <= 8; m <<= 1) mt = fmaxf(mt, __shfl_xor(mt, m));
      const float mnew = fmaxf(mrun[i], mt);
      const float fr = __expf(mrun[i] - mnew);
      mrun[i] = mnew;
      float ps = 0.f;
      #pragma unroll
      for (int ns = 0; ns < 4; ++ns) { float p = __expf(sv[ns][i] - mnew); sv[ns][i] = p; ps += p; }
      #pragma unroll
      for (int m = 1; m <= 8; m <<= 1) ps += __shfl_xor(ps, m);
      lrun[i] = lrun[i] * fr + ps;
      #pragma unroll
      for (int ds = 0; ds < 4; ++ds) oacc[ds][i] *= fr;
    }
    #pragma unroll
    for (int ns = 0; ns < 4; ++ns)
      #pragma unroll
      for (int i = 0; i < 4; ++i) {
        const int row = w * 16 + lg * 4 + i;
        const int cb = (ns * 16 + lc) * 2;
        *(unsigned short*)((char*)Ps + row * 128 + (cb ^ ((row & 7) << 4))) = f2bf(sv[ns][i]);
      }
    #pragma unroll
    for (int kc = 0; kc < 2; ++kc) {
      bf16x8 pa = read_swz(Ps, w * 16 + lc, kc * 64 + lg * 16);
      #pragma unroll
      for (int ds = 0; ds < 4; ++ds) {
        bf16x8 vb = read_swz(Vts, ds * 16 + lc, kc * 64 + lg * 16);
        oacc[ds] = mfma16(pa, vb, oacc[ds]);
      }
    }
    __syncthreads();
  }

  // ---- instruct branch ----
  {
    stage_tile_swz(IKg + (size_t)bh * 4096, 64, Ks, w, lane);
    stage_tile_swz(IVtg + (size_t)bh * 4096, 64, Vts, w, lane);
    __syncthreads();
    f32x4 sacc[4];
    #pragma unroll
    for (int ns = 0; ns < 4; ++ns) sacc[ns] = (f32x4){0.f, 0.f, 0.f, 0.f};
    #pragma unroll
    for (int kc = 0; kc < 2; ++kc)
      #pragma unroll
      for (int ns = 0; ns < 4; ++ns) {
        bf16x8 kb = read_swz(Ks, ns * 16 + lc, kc * 64 + lg * 16);
        sacc[ns] = mfma16(qa[kc], kb, sacc[ns]);
      }
    float sv[4][4], isum[4];
    #pragma unroll
    for (int ns = 0; ns < 4; ++ns) {
      const float mk = imask[b * SIN + ns * 16 + lc];
      #pragma unroll
      for (int i = 0; i < 4; ++i) sv[ns][i] = sacc[ns][i] * scale + mk;
    }
    #pragma unroll
    for (int i = 0; i < 4; ++i) {
      float mt = fmaxf(fmaxf(sv[0][i], sv[1][i]), fmaxf(sv[2][i], sv[3][i]));
      #pragma unroll
      for (int m = 1; m <= 8; m <<= 1) mt = fmaxf(mt, __shfl_xor(mt, m));
      float ps = 0.f;
      #pragma unroll
      for (int ns = 0; ns < 4; ++ns) { float p = __expf(sv[ns][i] - mt); sv[ns][i] = p; ps += p; }
      #pragma unroll
      for (int m = 1; m <= 8; m <<= 1) ps += __shfl_xor(ps, m);
      isum[i] = ps;
    }
    #pragma unroll
    for (int ns = 0; ns < 4; ++ns)
      #pragma unroll
      for (int i = 0; i < 4; ++i) {
        const int row = w * 16 + lg * 4 + i;
        const int cb = (ns * 16 + lc) * 2;
        *(unsigned short*)((char*)Ps + row * 128 + (cb ^ ((row & 7) << 4))) = f2bf(sv[ns][i]);
      }
    f32x4 iacc[4];
    #pragma unroll
    for (int ds = 0; ds < 4; ++ds) iacc[ds] = (f32x4){0.f, 0.f, 0.f, 0.f};
    #pragma unroll
    for (int kc = 0; kc < 2; ++kc) {
      bf16x8 pa = read_swz(Ps, w * 16 + lc, kc * 64 + lg * 16);
      #pragma unroll
      for (int ds = 0; ds < 4; ++ds) {
        bf16x8 vb = read_swz(Vts, ds * 16 + lc, kc * 64 + lg * 16);
        iacc[ds] = mfma16(pa, vb, iacc[ds]);
      }
    }
    const float tg = tanhf(gate[h]);
    #pragma unroll
    for (int ds = 0; ds < 4; ++ds)
      #pragma unroll
      for (int i = 0; i < 4; ++i) {
        const int li = w * 16 + lg * 4 + i;
        const float val = oacc[ds][i] / lrun[i] + tg * (iacc[ds][i] / isum[i]);
        out[(size_t)(b * SEQ + l0 + li) * 1024 + h * 64 + ds * 16 + lc] = val;
      }
  }
}

// ---------------- launch ----------------

extern "C" void kernel_launch(void* const* d_in, const int* in_sizes, int n_in,
                              void* d_out, int out_size, void* d_ws, size_t ws_size,
                              hipStream_t stream) {
  (void)in_sizes; (void)n_in; (void)out_size; (void)ws_size;
  const float* hs    = (const float*)d_in[0];
  const float* ihs   = (const float*)d_in[1];
  const float* mask  = (const float*)d_in[2];
  const float* imask = (const float*)d_in[3];
  const float* Wq    = (const float*)d_in[4];
  const float* bq    = (const float*)d_in[5];
  const float* Wk    = (const float*)d_in[6];
  const float* bk    = (const float*)d_in[7];
  const float* Wv    = (const float*)d_in[8];
  const float* bv    = (const float*)d_in[9];
  const float* de    = (const float*)d_in[10];
  const float* gate  = (const float*)d_in[11];
  float* out = (float*)d_out;

  char* ws = (char*)d_ws;
  size_t off = 0;
  auto alloc = [&](size_t bytes) -> void* {
    void* p = ws + off;
    off += (bytes + 255) & ~(size_t)255;
    return p;
  };
  unsigned short* X    = (unsigned short*)alloc((size_t)4608 * 1024 * 2);
  unsigned short* Wt   = (unsigned short*)alloc((size_t)3072 * 1024 * 2);
  unsigned short* E    = (unsigned short*)alloc((size_t)1024 * 64 * 2);
  unsigned short* Qb   = (unsigned short*)alloc((size_t)8 * 16 * 512 * 64 * 2);
  unsigned short* Kb   = (unsigned short*)alloc((size_t)8 * 16 * 512 * 64 * 2);
  unsigned short* Vtb  = (unsigned short*)alloc((size_t)8 * 16 * 64 * 512 * 2);
  unsigned short* IKb  = (unsigned short*)alloc((size_t)8 * 16 * 64 * 64 * 2);
  unsigned short* IVtb = (unsigned short*)alloc((size_t)8 * 16 * 64 * 64 * 2);
  unsigned short* Bias = (unsigned short*)alloc((size_t)128 * 64 * 4096 * 2);  // 64 MiB

  k_convert_x<<<4608, 256, 0, stream>>>(hs, ihs, X);
  k_convert_w<<<dim3(16, 16, 3), 256, 0, stream>>>(Wq, Wk, Wv, Wt);
  k_convert_e<<<64, 256, 0, stream>>>(de, E);
  k_gemm<<<dim3(24, 36), 256, 0, stream>>>(X, Wt, bq, bk, bv, Qb, Kb, Vtb, IKb, IVtb);
  k_bias<<<dim3(8, 8, 128), 256, 0, stream>>>(Qb, Kb, E, Bias);
  k_attn<<<dim3(8, 16, 8), 256, 0, stream>>>(Qb, Kb, Vtb, IKb, IVtb, Bias, mask, imask, gate, out);
}